// Round 1
// 334.629 us; speedup vs baseline: 1.1237x; 1.1237x over previous
//
#include <hip/hip_runtime.h>

// ---------- types ----------
typedef __attribute__((ext_vector_type(8))) short bf16x8;   // 8 bf16 = 4 VGPR
typedef __attribute__((ext_vector_type(4))) float f32x4;    // 16x16 MFMA C/D frag
typedef __attribute__((ext_vector_type(16))) float f32x16;  // 32x32 MFMA C/D frag

__device__ __forceinline__ short f2b(float f) {
  union { unsigned u; float f; } c;
  c.f = f;
  unsigned r = (c.u + 0x7FFFu + ((c.u >> 16) & 1u)) >> 16;  // RNE
  return (short)r;
}

// v_cvt_pk_bf16_f32: pack two f32 -> one u32 of 2 bf16 (no builtin on gfx950)
__device__ __forceinline__ int cvt_pk_bf16(float lo, float hi) {
  int r;
  asm("v_cvt_pk_bf16_f32 %0, %1, %2" : "=v"(r) : "v"(lo), "v"(hi));
  return r;
}

// v_permlane32_swap_b32: a' = [a.lo | b.lo], b' = [a.hi | b.hi]
__device__ __forceinline__ void plswap(int& a, int& b) {
  asm volatile("v_permlane32_swap_b32 %0, %1" : "+v"(a), "+v"(b));
}

// async global->LDS, 16B per lane
__device__ __forceinline__ void async16(const void* g, void* l) {
  __builtin_amdgcn_global_load_lds(
      (const __attribute__((address_space(1))) unsigned*)g,
      (__attribute__((address_space(3))) unsigned*)l, 16, 0, 0);
}

// ---------------------------------------------------------------------------
// fp32 -> bf16 conversion pre-pass
// ---------------------------------------------------------------------------
__global__ __launch_bounds__(256)
void f32_to_bf16(const float* __restrict__ src, short* __restrict__ dst, int n) {
  int i = (blockIdx.x * blockDim.x + threadIdx.x) * 4;
  if (i < n) {
    float4 v = *(const float4*)(src + i);
    short4 o;
    o.x = f2b(v.x); o.y = f2b(v.y); o.z = f2b(v.z); o.w = f2b(v.w);
    *(short4*)(dst + i) = o;
  }
}

// ---------------------------------------------------------------------------
// Generic GEMM: C[M,N] = A @ Bw^T + bias (used for out-projection, fp32 out)
// ---------------------------------------------------------------------------
template <bool F32OUT>
__global__ __launch_bounds__(256)
void gemm_bt_bias(const short* __restrict__ A, const short* __restrict__ Bw,
                  const float* __restrict__ bias, void* __restrict__ Cv,
                  int M, int N, int K) {
  __shared__ short lsA[128 * 32];
  __shared__ short lsB[128 * 32];
  const int tid  = threadIdx.x;
  const int wave = tid >> 6, lane = tid & 63;
  const int quad = lane >> 4, lrow = lane & 15;
  const int m0 = blockIdx.y * 128, n0 = blockIdx.x * 128;
  const int wm = (wave >> 1) * 64, wn = (wave & 1) * 64;

  f32x4 zero = {0.f, 0.f, 0.f, 0.f};
  f32x4 acc[4][4];
#pragma unroll
  for (int i = 0; i < 4; i++)
#pragma unroll
    for (int j = 0; j < 4; j++) acc[i][j] = zero;

  const int r0 = tid >> 2, c0 = (tid & 3) * 8;
  const short* Ab  = A  + (size_t)(m0 + r0) * K + c0;
  const short* Ab2 = A  + (size_t)(m0 + r0 + 64) * K + c0;
  const short* Bb  = Bw + (size_t)(n0 + r0) * K + c0;
  const short* Bb2 = Bw + (size_t)(n0 + r0 + 64) * K + c0;

  for (int k0 = 0; k0 < K; k0 += 32) {
    async16(Ab  + k0, lsA + tid * 8);
    async16(Ab2 + k0, lsA + (tid + 256) * 8);
    async16(Bb  + k0, lsB + tid * 8);
    async16(Bb2 + k0, lsB + (tid + 256) * 8);
    __syncthreads();

    bf16x8 af[4], bfr[4];
#pragma unroll
    for (int i = 0; i < 4; i++)
      af[i] = *(const bf16x8*)(lsA + (wm + i * 16 + lrow) * 32 + quad * 8);
#pragma unroll
    for (int j = 0; j < 4; j++)
      bfr[j] = *(const bf16x8*)(lsB + (wn + j * 16 + lrow) * 32 + quad * 8);
#pragma unroll
    for (int i = 0; i < 4; i++)
#pragma unroll
      for (int j = 0; j < 4; j++)
        acc[i][j] = __builtin_amdgcn_mfma_f32_16x16x32_bf16(af[i], bfr[j], acc[i][j], 0, 0, 0);
    __syncthreads();
  }

#pragma unroll
  for (int j = 0; j < 4; j++) {
    const int col = n0 + wn + j * 16 + lrow;
    const float bv = bias[col];
#pragma unroll
    for (int i = 0; i < 4; i++) {
      const int rowb = m0 + wm + i * 16 + quad * 4;
#pragma unroll
      for (int r = 0; r < 4; r++) {
        const float val = acc[i][j][r] + bv;
        if (F32OUT)
          ((float*)Cv)[(size_t)(rowb + r) * N + col] = val;
        else
          ((short*)Cv)[(size_t)(rowb + r) * N + col] = f2b(val);
      }
    }
  }
}

// ---------------------------------------------------------------------------
// Fused QKV GEMM: Bw is the contiguous [3072][2048] concat of wq|wk|wv in ws.
// Q output is pre-scaled by 0.125*log2(e) so the flash kernel can use exp2
// directly (softmax scale folded; normalization cancels the rest).
// ---------------------------------------------------------------------------
__global__ __launch_bounds__(256)
void gemm_qkv(const short* __restrict__ A, const short* __restrict__ Bw,
              const float* __restrict__ bq, const float* __restrict__ bk,
              const float* __restrict__ bv,
              short* __restrict__ Qo, short* __restrict__ Ko, short* __restrict__ Vo) {
  const int K = 2048;
  __shared__ short lsA[128 * 32];
  __shared__ short lsB[128 * 32];
  const int tid  = threadIdx.x;
  const int wave = tid >> 6, lane = tid & 63;
  const int quad = lane >> 4, lrow = lane & 15;
  const int m0 = blockIdx.y * 128, n0 = blockIdx.x * 128;
  const int wm = (wave >> 1) * 64, wn = (wave & 1) * 64;

  f32x4 zero = {0.f, 0.f, 0.f, 0.f};
  f32x4 acc[4][4];
#pragma unroll
  for (int i = 0; i < 4; i++)
#pragma unroll
    for (int j = 0; j < 4; j++) acc[i][j] = zero;

  const int r0 = tid >> 2, c0 = (tid & 3) * 8;
  const short* Ab  = A  + (size_t)(m0 + r0) * K + c0;
  const short* Ab2 = A  + (size_t)(m0 + r0 + 64) * K + c0;
  const short* Bb  = Bw + (size_t)(n0 + r0) * K + c0;
  const short* Bb2 = Bw + (size_t)(n0 + r0 + 64) * K + c0;

  for (int k0 = 0; k0 < K; k0 += 32) {
    async16(Ab  + k0, lsA + tid * 8);
    async16(Ab2 + k0, lsA + (tid + 256) * 8);
    async16(Bb  + k0, lsB + tid * 8);
    async16(Bb2 + k0, lsB + (tid + 256) * 8);
    __syncthreads();

    bf16x8 af[4], bfr[4];
#pragma unroll
    for (int i = 0; i < 4; i++)
      af[i] = *(const bf16x8*)(lsA + (wm + i * 16 + lrow) * 32 + quad * 8);
#pragma unroll
    for (int j = 0; j < 4; j++)
      bfr[j] = *(const bf16x8*)(lsB + (wn + j * 16 + lrow) * 32 + quad * 8);
#pragma unroll
    for (int i = 0; i < 4; i++)
#pragma unroll
      for (int j = 0; j < 4; j++)
        acc[i][j] = __builtin_amdgcn_mfma_f32_16x16x32_bf16(af[i], bfr[j], acc[i][j], 0, 0, 0);
    __syncthreads();
  }

  // block-uniform scatter select; Q gets the softmax scale folded in
  short* base; int stride, coff; const float* bias;
  if (n0 < 2048)      { base = Qo; stride = 2048; bias = bq; coff = 0; }
  else if (n0 < 2560) { base = Ko; stride = 512;  bias = bk; coff = 2048; }
  else                { base = Vo; stride = 512;  bias = bv; coff = 2560; }
  const float qs = (n0 < 2048) ? 0.18033688011112043f : 1.0f;  // 0.125*log2(e)

#pragma unroll
  for (int j = 0; j < 4; j++) {
    const int lc = n0 + wn + j * 16 + lrow - coff;
    const float bvv = bias[lc];
#pragma unroll
    for (int i = 0; i < 4; i++) {
      const int rowb = m0 + wm + i * 16 + quad * 4;
#pragma unroll
      for (int r = 0; r < 4; r++)
        base[(size_t)(rowb + r) * stride + lc] = f2b((acc[i][j][r] + bvv) * qs);
    }
  }
}

// ---------------------------------------------------------------------------
// Flash GQA v4: 32x32x16 MFMA, swapped QK^T (S^T = K Q'^T) so each lane holds
// a full 32-key slice of P for its own q-row (q = lane&31). Softmax fully
// in-register: exp2 (scale pre-folded into Q), cvt_pk_bf16 packing,
// permlane32_swap redistribution into PV A-fragments. No P LDS round-trip,
// no Q staging, no ones-row: row-sums by tree adds. LDS 18.9 KiB.
// Block = kv-head x 4 q-heads x 32 q-rows; XCD-swizzled blockIdx.
// ---------------------------------------------------------------------------
#define S_LEN 2048
#define HID   2048
#define KVD   512
#define ST    72

__global__ __launch_bounds__(256)
void gqa_flash(const short* __restrict__ Q, const short* __restrict__ Kb,
               const short* __restrict__ Vb, short* __restrict__ O) {
  __shared__ __align__(16) short lsK[64 * ST];    // [key][d]
  __shared__ __align__(16) short lsVt[64 * ST];   // [d][key]
  __shared__ float lsum[4][32];

  const int tid  = threadIdx.x;
  const int wave = tid >> 6, lane = tid & 63;
  const int l31  = lane & 31, hl = lane >> 5;

  // XCD-aware remap: all 64 q-tiles sharing one (b,kvh) K/V stream land on
  // one XCD residue class. grid=(64,16), dispatch id d=x+64y, XCD=d&7.
  const int d  = blockIdx.x + (blockIdx.y << 6);
  const int by = ((d & 7) << 1) | (d >> 9);
  const int qb = (d >> 3) & 63;
  const int b = by >> 3, kvh = by & 7;
  const int h = kvh * 4 + wave;
  const int q0 = qb * 32;

  // ---- Q B-frags direct from global (Q pre-scaled by 0.125*log2e) ----
  const short* Qrow = Q + (size_t)(b * S_LEN + q0 + l31) * HID + h * 64 + hl * 8;
  bf16x8 qf[4];
#pragma unroll
  for (int f = 0; f < 4; f++) qf[f] = *(const bf16x8*)(Qrow + f * 16);

  f32x16 o0, o1;
#pragma unroll
  for (int i = 0; i < 16; i++) { o0[i] = 0.f; o1[i] = 0.f; }
  float lloc = 0.f;

  const short* Kp = Kb + (size_t)b * S_LEN * KVD + kvh * 64;
  const short* Vp = Vb + (size_t)b * S_LEN * KVD + kvh * 64;

  const int keyA = tid >> 3, chK = (tid & 7) * 8;
  const int kpV = tid & 31, dcV = (tid >> 5) * 8;

  // prefetch tile 0
  bf16x8 kf0 = *(const bf16x8*)(Kp + (size_t)keyA * KVD + chK);
  bf16x8 kf1 = *(const bf16x8*)(Kp + (size_t)(keyA + 32) * KVD + chK);
  bf16x8 vf0 = *(const bf16x8*)(Vp + (size_t)(2 * kpV) * KVD + dcV);
  bf16x8 vf1 = *(const bf16x8*)(Vp + (size_t)(2 * kpV + 1) * KVD + dcV);

  for (int k0 = 0; k0 < S_LEN; k0 += 64) {
    // ---- commit prefetched K + V^T to LDS ----
    *(bf16x8*)(lsK + keyA * ST + chK) = kf0;
    *(bf16x8*)(lsK + (keyA + 32) * ST + chK) = kf1;
#pragma unroll
    for (int jj = 0; jj < 8; jj++) {
      unsigned pk = (unsigned)(unsigned short)vf0[jj] |
                    ((unsigned)(unsigned short)vf1[jj] << 16);
      *(unsigned*)(lsVt + (dcV + jj) * ST + 2 * kpV) = pk;
    }
    __syncthreads();

    // ---- prefetch next tile (latency hides under compute) ----
    const int kn = (k0 + 64) & (S_LEN - 1);
    kf0 = *(const bf16x8*)(Kp + (size_t)(kn + keyA) * KVD + chK);
    kf1 = *(const bf16x8*)(Kp + (size_t)(kn + keyA + 32) * KVD + chK);
    vf0 = *(const bf16x8*)(Vp + (size_t)(kn + 2 * kpV) * KVD + dcV);
    vf1 = *(const bf16x8*)(Vp + (size_t)(kn + 2 * kpV + 1) * KVD + dcV);

    // ---- S^T = K (Q')^T : two 32-key tiles, chained over d=64 ----
    f32x16 s0, s1;
#pragma unroll
    for (int i = 0; i < 16; i++) { s0[i] = 0.f; s1[i] = 0.f; }
    __builtin_amdgcn_s_setprio(1);
#pragma unroll
    for (int f = 0; f < 4; f++) {
      bf16x8 ka = *(const bf16x8*)(lsK + l31 * ST + f * 16 + hl * 8);
      bf16x8 kb = *(const bf16x8*)(lsK + (32 + l31) * ST + f * 16 + hl * 8);
      s0 = __builtin_amdgcn_mfma_f32_32x32x16_bf16(ka, qf[f], s0, 0, 0, 0);
      s1 = __builtin_amdgcn_mfma_f32_32x32x16_bf16(kb, qf[f], s1, 0, 0, 0);
    }
    __builtin_amdgcn_s_setprio(0);

    // ---- p = exp2(s) in place (scale already folded into Q) ----
#pragma unroll
    for (int i = 0; i < 16; i++) {
      s0[i] = __builtin_amdgcn_exp2f(s0[i]);
      s1[i] = __builtin_amdgcn_exp2f(s1[i]);
    }
    // partial row-sum over this lane's 32 keys (q = l31); other 32 keys live
    // at lane^32 -> combined once in the epilogue
    {
      f32x16 ps = s0 + s1;
      float a0 = (ps[0] + ps[1]) + (ps[2] + ps[3]);
      float a1 = (ps[4] + ps[5]) + (ps[6] + ps[7]);
      float a2 = (ps[8] + ps[9]) + (ps[10] + ps[11]);
      float a3 = (ps[12] + ps[13]) + (ps[14] + ps[15]);
      lloc += (a0 + a1) + (a2 + a3);
    }
    // pack to bf16 pairs: P2[j][q] = keys (32j + 8(q>>1) + 4hl + 2(q&1) + {0,1})
    int P2[2][8];
#pragma unroll
    for (int qq = 0; qq < 8; qq++) {
      P2[0][qq] = cvt_pk_bf16(s0[2 * qq], s0[2 * qq + 1]);
      P2[1][qq] = cvt_pk_bf16(s1[2 * qq], s1[2 * qq + 1]);
    }

    // ---- O += P V : per 16-key group t, build A-frag via permlane32_swap ----
    __builtin_amdgcn_s_setprio(1);
#pragma unroll
    for (int t = 0; t < 4; t++) {
      const int j = t >> 1, b0 = (t & 1) * 4;
      int w0 = P2[j][b0 + 0], w2 = P2[j][b0 + 2];
      int w1 = P2[j][b0 + 1], w3 = P2[j][b0 + 3];
      plswap(w0, w2);   // w0 = keys(16t+8hl+0,1), w2 = keys(16t+8hl+4,5)
      plswap(w1, w3);   // w1 = keys(16t+8hl+2,3), w3 = keys(16t+8hl+6,7)
      union { unsigned u[4]; bf16x8 v; } pa;
      pa.u[0] = (unsigned)w0; pa.u[1] = (unsigned)w1;
      pa.u[2] = (unsigned)w2; pa.u[3] = (unsigned)w3;
      bf16x8 bv0 = *(const bf16x8*)(lsVt + l31 * ST + t * 16 + hl * 8);
      bf16x8 bv1 = *(const bf16x8*)(lsVt + (32 + l31) * ST + t * 16 + hl * 8);
      o0 = __builtin_amdgcn_mfma_f32_32x32x16_bf16(pa.v, bv0, o0, 0, 0, 0);
      o1 = __builtin_amdgcn_mfma_f32_32x32x16_bf16(pa.v, bv1, o1, 0, 0, 0);
    }
    __builtin_amdgcn_s_setprio(0);
    __syncthreads();
  }

  // ---- epilogue: combine the two key-halves' sums, normalize, store ----
  const float lfull = lloc + __shfl(lloc, lane ^ 32);
  if (lane < 32) lsum[wave][lane] = lfull;   // wave-private slot, no barrier
#pragma unroll
  for (int r = 0; r < 16; r++) {
    const int qrow = (r & 3) + 8 * (r >> 2) + 4 * hl;
    const float rl = 1.0f / lsum[wave][qrow];
    short* op = O + (size_t)(b * S_LEN + q0 + qrow) * HID + h * 64 + l31;
    op[0]  = f2b(o0[r] * rl);
    op[32] = f2b(o1[r] * rl);
  }
}

// ---------------------------------------------------------------------------
extern "C" void kernel_launch(void* const* d_in, const int* in_sizes, int n_in,
                              void* d_out, int out_size, void* d_ws, size_t ws_size,
                              hipStream_t stream) {
  const float* x  = (const float*)d_in[0];
  const float* wq = (const float*)d_in[1];
  const float* bq = (const float*)d_in[2];
  const float* wk = (const float*)d_in[3];
  const float* bk = (const float*)d_in[4];
  const float* wv = (const float*)d_in[5];
  const float* bv = (const float*)d_in[6];
  const float* wo = (const float*)d_in[7];
  const float* bo = (const float*)d_in[8];
  float* out = (float*)d_out;

  // wqb|wkb|wvb contiguous => single [3072][2048] QKV weight matrix
  short* xb  = (short*)d_ws;
  short* wqb = xb  + (size_t)4096 * 2048;
  short* wkb = wqb + (size_t)2048 * 2048;
  short* wvb = wkb + (size_t)512 * 2048;
  short* wob = wvb + (size_t)512 * 2048;
  short* Qb  = wob + (size_t)2048 * 2048;
  short* Kb  = Qb  + (size_t)4096 * 2048;
  short* Vb  = Kb  + (size_t)4096 * 512;
  short* AO  = Vb  + (size_t)4096 * 512;

  dim3 blk(256);
  f32_to_bf16<<<4096 * 2048 / 1024, blk, 0, stream>>>(x,  xb,  4096 * 2048);
  f32_to_bf16<<<2048 * 2048 / 1024, blk, 0, stream>>>(wq, wqb, 2048 * 2048);
  f32_to_bf16<<< 512 * 2048 / 1024, blk, 0, stream>>>(wk, wkb, 512 * 2048);
  f32_to_bf16<<< 512 * 2048 / 1024, blk, 0, stream>>>(wv, wvb, 512 * 2048);
  f32_to_bf16<<<2048 * 2048 / 1024, blk, 0, stream>>>(wo, wob, 2048 * 2048);

  gemm_qkv<<<dim3(3072 / 128, 4096 / 128), blk, 0, stream>>>(xb, wqb, bq, bk, bv, Qb, Kb, Vb);
  gqa_flash<<<dim3(2048 / 32, 16), blk, 0, stream>>>(Qb, Kb, Vb, AO);
  gemm_bt_bias<true><<<dim3(2048 / 128, 4096 / 128), blk, 0, stream>>>(AO, wob, bo, out, 4096, 2048, 2048);
}